// Round 14
// baseline (274.456 us; speedup 1.0000x reference)
//
#include <hip/hip_runtime.h>
#include <hip/hip_bf16.h>

// Match numpy: no FMA contraction anywhere that feeds the Jacobi pivots.
#pragma clang fp contract(off)

#define N 4096
#define CIN 64
#define COUT 64
#define ITERS 10
#define MAXS 32
#define CANDMAX 384

typedef unsigned long long u64;

// pack (|value|, col j): bigger value wins; tie -> smaller j
__device__ __forceinline__ u64 packkey(float v, unsigned j) {
    return ((u64)__float_as_uint(v) << 32) | (u64)(~j);
}
// global pivot key: (valbits, row-major flat idx asc on ties) in 56 bits
__device__ __forceinline__ u64 gkey(unsigned vb, unsigned row, unsigned col) {
    unsigned flat = (row << 12) | col;
    return ((u64)vb << 24) | (u64)((~flat) & 0xFFFFFFu);
}

// spectral filter dot-product term for (wn, o, i)
__device__ __forceinline__ float spec_term(float wn, int o, int i,
        const float2* __restrict__ hcT, const float4* __restrict__ rwT,
        const float4* __restrict__ iwT) {
    const float C2 = -0.41614683654714241f;   // cos(2.0)
    const float S2 = 0.90929742682568170f;    // sin(2.0)
    float2 hc = hcT[i * 64 + o];
    float hw = hc.x * wn;
    float t2v = hw * hw;
    float inv = 1.0f / (t2v + 1.0f);
    float c1 = (t2v - 1.0f) * inv;
    float s1 = (2.0f * hw) * inv;
    if (!(hw > 1e-5f)) { c1 = C2; s1 = S2; }
    float4 rwv = rwT[i * 64 + o];
    float4 iwv = iwT[i * 64 + o];
    float g = hc.y;
    float cj = c1, sj = s1;
    g += rwv.x * cj - iwv.x * sj;
    float cn = cj * c1 - sj * s1; float sn = sj * c1 + cj * s1; cj = cn; sj = sn;
    g += rwv.y * cj - iwv.y * sj;
    cn = cj * c1 - sj * s1; sn = sj * c1 + cj * s1; cj = cn; sj = sn;
    g += rwv.z * cj - iwv.z * sj;
    cn = cj * c1 - sj * s1; sn = sj * c1 + cj * s1; cj = cn; sj = sn;
    g += rwv.w * cj - iwv.w * sj;
    return g;
}

// ---------- setup ----------
__global__ void init_prep_k(int* __restrict__ deg, int* __restrict__ fill,
                            const float* __restrict__ hh, const float* __restrict__ cw,
                            const float* __restrict__ rw, const float* __restrict__ iw,
                            float2* __restrict__ hcT, float4* __restrict__ rwT,
                            float4* __restrict__ iwT) {
    int b = blockIdx.x;
    if (b < 16) {
        int i = b * 256 + threadIdx.x;
        deg[i] = 0; fill[i] = 0;
    } else {
        int idx = (b - 16) * 256 + threadIdx.x;   // 4096 = i*64+o
        int i = idx >> 6, o = idx & 63;
        int src = o * 64 + i;
        hcT[idx] = make_float2(hh[src], cw[src]);
        rwT[idx] = make_float4(rw[src * 4 + 0], rw[src * 4 + 1], rw[src * 4 + 2], rw[src * 4 + 3]);
        iwT[idx] = make_float4(iw[src * 4 + 0], iw[src * 4 + 1], iw[src * 4 + 2], iw[src * 4 + 3]);
    }
}

__global__ void edges1_k(const int* __restrict__ ei, int* __restrict__ deg, int E) {
    int e = blockIdx.x * 256 + threadIdx.x;
    if (e < E) atomicAdd(&deg[ei[e]], 1);
}

__global__ void __launch_bounds__(1024) scan_k(const int* __restrict__ deg,
                                               int* __restrict__ rowptr,
                                               float* __restrict__ dinv) {
    __shared__ int ps[1024];
    int t = threadIdx.x, b = t * 4;
    int d0 = deg[b], d1 = deg[b + 1], d2 = deg[b + 2], d3 = deg[b + 3];
    int local = d0 + d1 + d2 + d3;
    ps[t] = local;
    __syncthreads();
    for (int off = 1; off < 1024; off <<= 1) {
        int v = (t >= off) ? ps[t - off] : 0;
        __syncthreads();
        ps[t] += v;
        __syncthreads();
    }
    int excl = ps[t] - local;
    rowptr[b] = excl; rowptr[b + 1] = excl + d0;
    rowptr[b + 2] = excl + d0 + d1; rowptr[b + 3] = excl + d0 + d1 + d2;
    if (t == 1023) rowptr[4096] = ps[1023];
    dinv[b]     = d0 > 0 ? 1.0f / sqrtf((float)d0) : 0.0f;
    dinv[b + 1] = d1 > 0 ? 1.0f / sqrtf((float)d1) : 0.0f;
    dinv[b + 2] = d2 > 0 ? 1.0f / sqrtf((float)d2) : 0.0f;
    dinv[b + 3] = d3 > 0 ? 1.0f / sqrtf((float)d3) : 0.0f;
}

__global__ void edges2_k(const int* __restrict__ ei, const int* __restrict__ rowptr,
                         int* __restrict__ fill, int* __restrict__ colidx, int E) {
    int e = blockIdx.x * 256 + threadIdx.x;
    if (e < E) {
        int r = ei[e], c = ei[E + e];
        int pos = rowptr[r] + atomicAdd(&fill[r], 1);
        colidx[pos] = c;
    }
}

// Sparse per-row top-24 (distinct columns, sorted desc by (val, -col)), diag, y=x.
__global__ void __launch_bounds__(64) rowmax0_k(
        const int* __restrict__ rowptr, const int* __restrict__ colidx,
        const float* __restrict__ dinv, const float* __restrict__ x,
        float* __restrict__ y, float* __restrict__ diag, u64* __restrict__ top24T) {
    const int i = blockIdx.x, t = threadIdx.x;
    __shared__ float row[N];        // touched-sparse
    __shared__ u64 cand[CANDMAX];
    __shared__ int scnt;
    int rs = rowptr[i], re = rowptr[i + 1];
    if (t == 0) { scnt = 0; row[i] = 0.0f; }
    __syncthreads();
    for (int e = rs + t; e < re; e += 64) { int c2 = colidx[e]; if (c2 >= i) row[c2] = 0.0f; }
    __syncthreads();
    for (int e = rs + t; e < re; e += 64) { int c2 = colidx[e]; if (c2 >= i) atomicAdd(&row[c2], 1.0f); }
    __syncthreads();
    float di = dinv[i];
    for (int e = rs + t; e < re; e += 64) {
        int c2 = colidx[e];
        if (c2 > i) {
            float v = -((di * row[c2]) * dinv[c2]);
            int idx = atomicAdd(&scnt, 1);
            if (idx < CANDMAX) cand[idx] = packkey(fabsf(v), (unsigned)c2);
        }
    }
    __syncthreads();
    int L = scnt < CANDMAX ? scnt : CANDMAX;
    for (int r = 0; r < 24; ++r) {
        u64 best = 0ull;
        for (int idx = t; idx < L; idx += 64) { u64 cc = cand[idx]; if (cc > best) best = cc; }
        for (int off = 32; off; off >>= 1) { u64 o = __shfl_xor(best, off, 64); if (o > best) best = o; }
        if (t == 0) top24T[(size_t)r * N + i] = best;
        for (int idx = t; idx < L; idx += 64) { if (cand[idx] == best) cand[idx] = 0ull; }
        __syncthreads();
    }
    if (t == 0) diag[i] = 1.0f - ((di * row[i]) * di);
    y[i * CIN + t] = x[i * CIN + t];
}

// ---------- fused: block 0 = persistent Jacobi; blocks 1..256 = spectral ----------
// Spectral blocks use PRE-jacobi diag/y, valid for all non-pivot rows (jacobi only
// modifies pivot rows' y/diag). Pivot-row z entries are garbage (racy, discarded);
// store_fused_k recomputes them from final state.
__global__ void __launch_bounds__(1024) jacspec_k(
        const int* __restrict__ rowptr, const int* __restrict__ colidx,
        const float* __restrict__ dinv,
        float* __restrict__ diag, const u64* __restrict__ top24T, float* __restrict__ y,
        float* __restrict__ rowS, float* __restrict__ colS,
        int* __restrict__ dslotG, int* __restrict__ slistG, int* __restrict__ nslotsG,
        int* __restrict__ rotk, int* __restrict__ rotl,
        float* __restrict__ rotc, float* __restrict__ rotsv,
        const float2* __restrict__ hcT, const float4* __restrict__ rwT,
        const float4* __restrict__ iwT, float* __restrict__ z) {
    __shared__ __align__(16) float cntK[N], cntL[N];   // counts in, new col values out
    __shared__ __align__(16) float rowKst[N], rowLst[N]; // new row k,l stash
    __shared__ __align__(16) float dinvL[N];
    __shared__ u64 rmaxL[N];
    __shared__ float rvalL[N];
    __shared__ float diagL[N];
    __shared__ short dslotL[N];
    __shared__ u64 rmaxSlot[MAXS];
    __shared__ u64 w16[16], w16b[16];
    __shared__ float ovRowK[MAXS], ovRowL[MAXS], ovColK[MAXS], ovColL[MAXS];
    __shared__ int slistL[MAXS];
    __shared__ unsigned short sdirty[64];
    __shared__ int S_snd;
    const int t = threadIdx.x;

    if (blockIdx.x != 0) {
        // ---------------- spectral branch (reuses cntK as saux) ----------------
        float (*saux)[CIN] = (float(*)[CIN])cntK;
        int o = t & 63, nl = t >> 6;
        int n = (blockIdx.x - 1) * 16 + nl;
        saux[nl][o] = y[n * CIN + o];
        __syncthreads();
        float wn = diag[n];
        float acc = 0.0f;
        for (int i = 0; i < CIN; ++i)
            acc += spec_term(wn, o, i, hcT, rwT, iwT) * saux[nl][i];
        z[(size_t)n * COUT + o] = acc;
        return;
    }

    // ---------------- jacobi branch (block 0) ----------------
    // prologue: LDS state + zero cnt + first pivot
    u64 mb0 = 0ull;
    for (int i = t; i < N; i += 1024) {
        u64 kk = top24T[i];
        rmaxL[i] = kk;
        rvalL[i] = -__uint_as_float((unsigned)(kk >> 32));
        diagL[i] = diag[i];
        dinvL[i] = dinv[i];
        dslotL[i] = -1;
        cntK[i] = 0.0f;
        cntL[i] = 0.0f;
        unsigned col = (~(unsigned)kk) & 4095u;
        u64 gk = gkey((unsigned)(kk >> 32), (unsigned)i, col);
        if (gk > mb0) mb0 = gk;
    }
    for (int off = 32; off; off >>= 1) { u64 o = __shfl_down(mb0, off, 64); if (o > mb0) mb0 = o; }
    if ((t & 63) == 0) w16[t >> 6] = mb0;
    __syncthreads();
    u64 pivot = w16[0];
    for (int w = 1; w < 16; ++w) if (w16[w] > pivot) pivot = w16[w];
    int nsCur = 0;   // per-thread slot count, identical across threads

    for (int it = 0; it < ITERS; ++it) {
        // ---- alpha+beta (merged, no barrier): redundant decode + commits ----
        unsigned flat = (~(unsigned)pivot) & 0xFFFFFFu;
        const int k = (int)(flat >> 12), l = (int)(flat & 4095u);
        const float akl = rvalL[k];
        const float akk = diagL[k], all_ = diagL[l];
        float aDiff = all_ - akk;
        float akl_safe = (akl == 0.0f) ? 1.0f : akl;
        float aDiff_safe = (aDiff == 0.0f) ? 1.0f : aDiff;
        float phi = aDiff / (2.0f * akl_safe);
        float t2 = 1.0f / (fabsf(phi) + sqrtf(phi * phi + 1.0f));
        t2 = (phi < 0.0f) ? -t2 : t2;
        float t1 = akl / aDiff_safe;
        float tt = (fabsf(akl) < fabsf(aDiff) * 1e-36f) ? t1 : t2;
        const float c = 1.0f / sqrtf(tt * tt + 1.0f);
        const float s = tt * c;
        float a1kk = c * akk - s * akl;
        float a1kl = s * akk + c * akl;
        float a1lk = c * akl - s * all_;   // a_{l,k} == a_{k,l}
        float a1ll = s * akl + c * all_;
        const float a2kk = c * a1kk - s * a1lk;
        const float a2ll = s * a1kl + c * a1ll;
        // slot lookup via slistL scan (t0's appends land at >= nsCur: race-free)
        int ok = -1, ol = -1;
        for (int sl = 0; sl < nsCur; ++sl) {
            int js = slistL[sl];
            if (js == k) ok = sl;
            if (js == l) ol = sl;
        }
        const int nold = nsCur;
        const bool freshK = (ok < 0), freshL = (ol < 0);
        int sk2 = ok, sl3 = ol;
        { int ns = nsCur; if (freshK) sk2 = ns++; if (freshL) sl3 = ns++; nsCur = ns; }
        const int slotk = sk2, slotl = sl3;
        const float dk = dinvL[k], dl = dinvL[l];
        if (t == 0) {
            rotk[it] = k; rotl[it] = l; rotc[it] = c; rotsv[it] = s;
            if (freshK) { slistL[slotk] = k; dslotL[k] = (short)slotk; }
            if (freshL) { slistL[slotl] = l; dslotL[l] = (short)slotl; }
            S_snd = 0;
        }
        if (t < CIN) {
            float yk = y[k * CIN + t], yl = y[l * CIN + t];
            y[k * CIN + t] = c * yk - s * yl;
            y[l * CIN + t] = s * yk + c * yl;
        }
        if (t >= 64 && t < 64 + nold) {
            int sl2 = t - 64;
            if (freshK) { ovRowK[sl2] = colS[(size_t)sl2 * N + k]; ovColK[sl2] = rowS[(size_t)sl2 * N + k]; }
            if (freshL) { ovRowL[sl2] = colS[(size_t)sl2 * N + l]; ovColL[sl2] = rowS[(size_t)sl2 * N + l]; }
        }
        if (freshK) for (int e = rowptr[k] + t; e < rowptr[k + 1]; e += 1024) atomicAdd(&cntK[colidx[e]], 1.0f);
        if (freshL) for (int e = rowptr[l] + t; e < rowptr[l + 1]; e += 1024) atomicAdd(&cntL[colidx[e]], 1.0f);
        __syncthreads();  // B
        // ---- (a): build + overlay + rotate + store + stash ----
        u64 bk = packkey(0.0f, 4095u), bl = packkey(0.0f, 4095u);
        {
            const int j0 = t * 4;
            float4 dj4 = *reinterpret_cast<const float4*>(dinvL + j0);
            float4 bK4, bL4, cK4, cL4;
            if (freshK) {
                float4 cnt = *reinterpret_cast<const float4*>(cntK + j0);
#pragma unroll
                for (int m = 0; m < 4; ++m) {
                    float cn = (&cnt.x)[m], dj = (&dj4.x)[m];
                    (&bK4.x)[m] = -((dk * cn) * dj);
                    (&cK4.x)[m] = -((dj * cn) * dk);
                }
            } else {
                bK4 = *reinterpret_cast<const float4*>(rowS + (size_t)ok * N + j0);
                cK4 = *reinterpret_cast<const float4*>(colS + (size_t)ok * N + j0);
            }
            if (freshL) {
                float4 cnt = *reinterpret_cast<const float4*>(cntL + j0);
#pragma unroll
                for (int m = 0; m < 4; ++m) {
                    float cn = (&cnt.x)[m], dj = (&dj4.x)[m];
                    (&bL4.x)[m] = -((dl * cn) * dj);
                    (&cL4.x)[m] = -((dj * cn) * dl);
                }
            } else {
                bL4 = *reinterpret_cast<const float4*>(rowS + (size_t)ol * N + j0);
                cL4 = *reinterpret_cast<const float4*>(colS + (size_t)ol * N + j0);
            }
            float4 nrK4, nrL4, ncK4, ncL4;
#pragma unroll
            for (int m = 0; m < 4; ++m) {
                int j = j0 + m;
                float bK = (&bK4.x)[m], bL = (&bL4.x)[m];
                float cK = (&cK4.x)[m], cL = (&cL4.x)[m];
                float nrk, nrl, nck, ncl;
                if (j == k)      { nrk = a2kk; nrl = 0.0f; nck = a2kk; ncl = 0.0f; }
                else if (j == l) { nrk = 0.0f; nrl = a2ll; nck = 0.0f; ncl = a2ll; }
                else {
                    int sl2 = dslotL[j];
                    if (sl2 >= 0 && sl2 < nold) {
                        if (freshK) { bK = ovRowK[sl2]; cK = ovColK[sl2]; }
                        if (freshL) { bL = ovRowL[sl2]; cL = ovColL[sl2]; }
                    }
                    nrk = c * bK - s * bL; nrl = s * bK + c * bL;
                    nck = c * cK - s * cL; ncl = s * cK + c * cL;
                }
                (&nrK4.x)[m] = nrk; (&nrL4.x)[m] = nrl;
                (&ncK4.x)[m] = nck; (&ncL4.x)[m] = ncl;
                if (j > k) { u64 kk = packkey(fabsf(nrk), (unsigned)j); if (kk > bk) bk = kk; }
                if (j > l) { u64 kk = packkey(fabsf(nrl), (unsigned)j); if (kk > bl) bl = kk; }
            }
            *reinterpret_cast<float4*>(rowS + (size_t)slotk * N + j0) = nrK4;
            *reinterpret_cast<float4*>(rowS + (size_t)slotl * N + j0) = nrL4;
            *reinterpret_cast<float4*>(colS + (size_t)slotk * N + j0) = ncK4;
            *reinterpret_cast<float4*>(colS + (size_t)slotl * N + j0) = ncL4;
            *reinterpret_cast<float4*>(rowKst + j0) = nrK4;   // LDS stashes
            *reinterpret_cast<float4*>(rowLst + j0) = nrL4;
            *reinterpret_cast<float4*>(cntK + j0) = ncK4;
            *reinterpret_cast<float4*>(cntL + j0) = ncL4;
        }
        for (int off = 32; off; off >>= 1) {
            u64 o = __shfl_down(bk, off, 64); if (o > bk) bk = o;
            u64 o2 = __shfl_down(bl, off, 64); if (o2 > bl) bl = o2;
        }
        if ((t & 63) == 0) { w16[t >> 6] = bk; w16b[t >> 6] = bl; }
        __syncthreads();  // C
        // ---- (b): finalize k/l (LDS), patches (LDS reads), coalesced merge ----
        if (t == 0) {
            u64 b1 = w16[0], b2 = w16b[0];
            for (int w = 1; w < 16; ++w) { if (w16[w] > b1) b1 = w16[w]; if (w16b[w] > b2) b2 = w16b[w]; }
            unsigned j1 = (~(unsigned)b1) & 4095u, j2 = (~(unsigned)b2) & 4095u;
            rvalL[k] = rowKst[j1];
            rvalL[l] = rowLst[j2];
            rmaxSlot[slotk] = gkey((unsigned)(b1 >> 32), (unsigned)k, j1);
            rmaxSlot[slotl] = gkey((unsigned)(b2 >> 32), (unsigned)l, j2);
            diagL[k] = a2kk; diagL[l] = a2ll;   // deferred (alpha reads diagL)
        }
        if (t >= 64 && t < 64 + nold) {
            int sl2 = t - 64;
            int js = slistL[sl2];
            if (js != k && js != l) {
                float vkj = rowKst[js];   // new a_{k,js}
                float vlj = rowLst[js];   // new a_{l,js}
                float vjk = cntK[js];     // new a_{js,k}
                float vjl = cntL[js];     // new a_{js,l}
                colS[(size_t)sl2 * N + k] = vkj;
                colS[(size_t)sl2 * N + l] = vlj;
                rowS[(size_t)sl2 * N + k] = vjk;
                rowS[(size_t)sl2 * N + l] = vjl;
                u64 cached = rmaxSlot[sl2];
                unsigned cj = ((~(unsigned)cached) & 0xFFFFFFu) & 4095u;
                bool kc = (k > js), lc = (l > js);
                u64 ck2 = kc ? gkey(__float_as_uint(fabsf(vjk)), (unsigned)js, (unsigned)k) : 0ull;
                u64 cl2 = lc ? gkey(__float_as_uint(fabsf(vjl)), (unsigned)js, (unsigned)l) : 0ull;
                bool stale = false; u64 base = cached; bool useOld = true;
                if (kc && cj == (unsigned)k)      { if (ck2 < cached) stale = true; else { base = 0ull; useOld = false; } }
                else if (lc && cj == (unsigned)l) { if (cl2 < cached) stale = true; else { base = 0ull; useOld = false; } }
                if (!stale) {
                    if (kc || lc) {
                        u64 mm = base; float mv = useOld ? rvalL[js] : 0.0f;
                        if (ck2 > mm) { mm = ck2; mv = vjk; }
                        if (cl2 > mm) { mm = cl2; mv = vjl; }
                        rmaxSlot[sl2] = mm; rvalL[js] = mv;
                    }
                } else { int d2 = atomicAdd(&S_snd, 1); sdirty[d2] = (unsigned short)sl2; }
            }
        }
        u64 myBest = 0ull;
#pragma unroll
        for (int m = 0; m < 4; ++m) {
            int j = t + 1024 * m;
            if (dslotL[j] >= 0) continue;            // slot rows (incl. k,l) via rmaxSlot
            float nck = cntK[j], ncl = cntL[j];
            u64 cached = rmaxL[j];
            unsigned cj = (~(unsigned)cached) & 4095u;
            bool kc = (k > j), lc = (l > j);
            u64 ck2 = kc ? packkey(fabsf(nck), (unsigned)k) : 0ull;
            u64 cl2 = lc ? packkey(fabsf(ncl), (unsigned)l) : 0ull;
            bool stale = false; u64 base = cached; bool useOld = true;
            if (kc && cj == (unsigned)k)      { if (ck2 < cached) stale = true; else { base = 0ull; useOld = false; } }
            else if (lc && cj == (unsigned)l) { if (cl2 < cached) stale = true; else { base = 0ull; useOld = false; } }
            if (!stale) {
                if (kc || lc) {
                    u64 mm = base; float mv = useOld ? rvalL[j] : 0.0f;
                    if (ck2 > mm) { mm = ck2; mv = nck; }
                    if (cl2 > mm) { mm = cl2; mv = ncl; }
                    rmaxL[j] = mm; rvalL[j] = mv;
                }
            } else {
                // fresh compute: static top-24 probe (early exit) + slots + k/l
                u64 bKey = 0ull; float bVal = 0.0f;
                for (int cc = 0; cc < 24; ++cc) {
                    u64 cand = top24T[(size_t)cc * N + j];
                    unsigned col = (~(unsigned)cand) & 4095u;
                    if (dslotL[col] < 0) {
                        bKey = cand;
                        bVal = -__uint_as_float((unsigned)(cand >> 32));
                        break;
                    }
                }
                for (int sl = 0; sl < nsCur; ++sl) {
                    if (sl == slotk || sl == slotl) continue;
                    int js = slistL[sl];
                    if (js > j) {
                        float v = colS[(size_t)sl * N + j];
                        u64 kk2 = packkey(fabsf(v), (unsigned)js);
                        if (kk2 > bKey) { bKey = kk2; bVal = v; }
                    }
                }
                if (kc && ck2 > bKey) { bKey = ck2; bVal = nck; }
                if (lc && cl2 > bKey) { bKey = cl2; bVal = ncl; }
                rmaxL[j] = bKey; rvalL[j] = bVal;
            }
            u64 fin = rmaxL[j];
            u64 gk = gkey((unsigned)(fin >> 32), (unsigned)j, (~(unsigned)fin) & 4095u);
            if (gk > myBest) myBest = gk;
        }
        __syncthreads();  // D
        // ---- post-D: zero cnt for next iter (dead here), dirty rescans, reduce ----
        const int nd = S_snd;
        {
            const int j0 = t * 4;
            float4 zz; zz.x = zz.y = zz.z = zz.w = 0.0f;
            *reinterpret_cast<float4*>(cntK + j0) = zz;
            *reinterpret_cast<float4*>(cntL + j0) = zz;
        }
        for (int d = 0; d < nd; ++d) {
            int sl2 = sdirty[d];
            int ir = slistL[sl2];
            u64 bb = packkey(0.0f, 4095u);
            int jb = t * 4;
            float4 v4 = *reinterpret_cast<const float4*>(rowS + (size_t)sl2 * N + jb);
#pragma unroll
            for (int m = 0; m < 4; ++m) {
                int j = jb + m;
                if (j > ir) {
                    u64 kk = packkey(fabsf((&v4.x)[m]), (unsigned)j);
                    if (kk > bb) bb = kk;
                }
            }
            for (int off = 32; off; off >>= 1) { u64 o = __shfl_down(bb, off, 64); if (o > bb) bb = o; }
            if ((t & 63) == 0) w16[t >> 6] = bb;
            __syncthreads();
            if (t == 0) {
                u64 b = w16[0];
                for (int w = 1; w < 16; ++w) if (w16[w] > b) b = w16[w];
                unsigned js2 = (~(unsigned)b) & 4095u;
                rmaxSlot[sl2] = gkey((unsigned)(b >> 32), (unsigned)ir, js2);
                rvalL[ir] = rowS[(size_t)sl2 * N + js2];
            }
            __syncthreads();
        }
        // ---- final pivot reduce: redundant decode ----
        if (t < nsCur) { u64 o2 = rmaxSlot[t]; if (o2 > myBest) myBest = o2; }
        for (int off = 32; off; off >>= 1) { u64 o = __shfl_down(myBest, off, 64); if (o > myBest) myBest = o; }
        if ((t & 63) == 0) w16[t >> 6] = myBest;
        __syncthreads();  // E
        pivot = w16[0];
        for (int w = 1; w < 16; ++w) if (w16[w] > pivot) pivot = w16[w];
    }
    // epilogue: mirror state for tail kernels
    for (int i = t; i < N; i += 1024) {
        diag[i] = diagL[i];
        dslotG[i] = (int)dslotL[i];
    }
    if (t < nsCur) slistG[t] = slistL[t];
    if (t == 0) *nslotsG = nsCur;
}

// ---------- store: non-pivot rows from z; pivot rows recomputed from final state ----------
__global__ void __launch_bounds__(1024) store_fused_k(
        const float* __restrict__ z, const float* __restrict__ bias,
        const int* __restrict__ dslot, const int* __restrict__ slistG,
        const int* __restrict__ nslotsG,
        const int* __restrict__ rotk, const int* __restrict__ rotl,
        const float* __restrict__ rotc, const float* __restrict__ rotsv,
        const float* __restrict__ diag, const float* __restrict__ y,
        const float2* __restrict__ hcT, const float4* __restrict__ rwT,
        const float4* __restrict__ iwT,
        float* __restrict__ out) {
    __shared__ float zloc[MAXS][COUT];
    int t = threadIdx.x;
    if (blockIdx.x < 1024) {
        int idx = blockIdx.x * 256 + (t & 255);
        if (t < 256) {
            int row = idx >> 6;
            if (dslot[row] < 0) out[idx] = z[idx] + bias[idx & 63];
        }
    } else {
        // pivot (slot) rows: spectral from FINAL diag/y + rotation chain + store
        int ns = *nslotsG;
        int o = t & 63, d = t >> 6;
        for (int dd = d; dd < ns; dd += 16) {
            int r = slistG[dd];
            float wn = diag[r];
            float acc = 0.0f;
            for (int i = 0; i < CIN; ++i)
                acc += spec_term(wn, o, i, hcT, rwT, iwT) * y[r * CIN + i];
            zloc[dd][o] = acc;
        }
        __syncthreads();
        if (t < 64) {
            for (int i = ITERS - 1; i >= 0; --i) {
                int k = rotk[i], l = rotl[i];
                float c = rotc[i], s = rotsv[i];
                int sk = dslot[k], sl = dslot[l];
                float zk = zloc[sk][t], zl = zloc[sl][t];
                zloc[sk][t] = c * zk + s * zl;
                zloc[sl][t] = -s * zk + c * zl;
            }
        }
        __syncthreads();
        for (int dd = d; dd < ns; dd += 16) {
            out[slistG[dd] * COUT + o] = zloc[dd][o] + bias[o];
        }
    }
}

extern "C" void kernel_launch(void* const* d_in, const int* in_sizes, int n_in,
                              void* d_out, int out_size, void* d_ws, size_t ws_size,
                              hipStream_t stream) {
    const float* x   = (const float*)d_in[0];
    const int*   ei  = (const int*)d_in[1];
    const float* rw  = (const float*)d_in[2];
    const float* iw  = (const float*)d_in[3];
    const float* hh  = (const float*)d_in[4];
    const float* cw  = (const float*)d_in[5];
    const float* bias= (const float*)d_in[6];
    float* out = (float*)d_out;

    // Workspace carve (~6.1 MB)
    float* rowS = (float*)d_ws;                 // MAXS*N
    float* colS = rowS + (size_t)MAXS * N;      // MAXS*N
    float* y    = colS + (size_t)MAXS * N;      // N*CIN
    float* z    = y + N * CIN;                  // N*COUT
    float2* hcT = (float2*)(z + N * COUT);      // 4096 float2
    float4* rwT = (float4*)(hcT + 4096);        // 4096 float4
    float4* iwT = rwT + 4096;                   // 4096 float4
    float* dinv = (float*)(iwT + 4096);         // 4096
    float* diag = dinv + N;                     // 4096
    u64* top24T = (u64*)(diag + N);             // 24*N u64
    int* rowptr = (int*)(top24T + 24 * (size_t)N); // 4097 (+pad)
    int* fill   = rowptr + 4100;                // 4096
    int* deg    = fill + N;                     // 4096
    int* slist  = deg + N;                      // 64
    int* nslots = slist + 64;                   // 4
    int* dslot  = nslots + 4;                   // 4096
    int* rotk   = dslot + N;                    // 16
    int* rotl   = rotk + 16;                    // 16
    float* rotc = (float*)(rotl + 16);          // 16
    float* rotsv= rotc + 16;                    // 16
    int* colidx = (int*)(rotsv + 16);           // E

    int E = in_sizes[1] / 2;                    // row half of edge_index
    int eb = (E + 255) / 256;

    init_prep_k<<<32, 256, 0, stream>>>(deg, fill, hh, cw, rw, iw, hcT, rwT, iwT);
    edges1_k<<<eb, 256, 0, stream>>>(ei, deg, E);
    scan_k<<<1, 1024, 0, stream>>>(deg, rowptr, dinv);
    edges2_k<<<eb, 256, 0, stream>>>(ei, rowptr, fill, colidx, E);
    rowmax0_k<<<N, 64, 0, stream>>>(rowptr, colidx, dinv, x, y, diag, top24T);

    jacspec_k<<<257, 1024, 0, stream>>>(rowptr, colidx, dinv, diag, top24T,
                                        y, rowS, colS, dslot, slist, nslots,
                                        rotk, rotl, rotc, rotsv,
                                        hcT, rwT, iwT, z);

    store_fused_k<<<1025, 1024, 0, stream>>>(z, bias, dslot, slist, nslots,
                                             rotk, rotl, rotc, rotsv,
                                             diag, y, hcT, rwT, iwT, out);
}

// Round 15
// 263.614 us; speedup vs baseline: 1.0411x; 1.0411x over previous
//
#include <hip/hip_runtime.h>
#include <hip/hip_bf16.h>

// Match numpy: no FMA contraction anywhere that feeds the Jacobi pivots.
#pragma clang fp contract(off)

#define N 4096
#define CIN 64
#define COUT 64
#define ITERS 10
#define MAXS 32
#define CANDMAX 384

typedef unsigned long long u64;

// pack (|value|, col j): bigger value wins; tie -> smaller j
__device__ __forceinline__ u64 packkey(float v, unsigned j) {
    return ((u64)__float_as_uint(v) << 32) | (u64)(~j);
}
// global pivot key: (valbits, row-major flat idx asc on ties) in 56 bits
__device__ __forceinline__ u64 gkey(unsigned vb, unsigned row, unsigned col) {
    unsigned flat = (row << 12) | col;
    return ((u64)vb << 24) | (u64)((~flat) & 0xFFFFFFu);
}

// ---------- setup ----------
__global__ void init_prep_k(int* __restrict__ deg, int* __restrict__ fill,
                            const float* __restrict__ hh, const float* __restrict__ cw,
                            const float* __restrict__ rw, const float* __restrict__ iw,
                            float2* __restrict__ hcT, float4* __restrict__ rwT,
                            float4* __restrict__ iwT) {
    int b = blockIdx.x;
    if (b < 16) {
        int i = b * 256 + threadIdx.x;
        deg[i] = 0; fill[i] = 0;
    } else {
        int idx = (b - 16) * 256 + threadIdx.x;   // 4096 = i*64+o
        int i = idx >> 6, o = idx & 63;
        int src = o * 64 + i;
        hcT[idx] = make_float2(hh[src], cw[src]);
        rwT[idx] = make_float4(rw[src * 4 + 0], rw[src * 4 + 1], rw[src * 4 + 2], rw[src * 4 + 3]);
        iwT[idx] = make_float4(iw[src * 4 + 0], iw[src * 4 + 1], iw[src * 4 + 2], iw[src * 4 + 3]);
    }
}

__global__ void edges1_k(const int* __restrict__ ei, int* __restrict__ deg, int E) {
    int e = blockIdx.x * 256 + threadIdx.x;
    if (e < E) atomicAdd(&deg[ei[e]], 1);
}

__global__ void __launch_bounds__(1024) scan_k(const int* __restrict__ deg,
                                               int* __restrict__ rowptr,
                                               float* __restrict__ dinv) {
    __shared__ int ps[1024];
    int t = threadIdx.x, b = t * 4;
    int d0 = deg[b], d1 = deg[b + 1], d2 = deg[b + 2], d3 = deg[b + 3];
    int local = d0 + d1 + d2 + d3;
    ps[t] = local;
    __syncthreads();
    for (int off = 1; off < 1024; off <<= 1) {
        int v = (t >= off) ? ps[t - off] : 0;
        __syncthreads();
        ps[t] += v;
        __syncthreads();
    }
    int excl = ps[t] - local;
    rowptr[b] = excl; rowptr[b + 1] = excl + d0;
    rowptr[b + 2] = excl + d0 + d1; rowptr[b + 3] = excl + d0 + d1 + d2;
    if (t == 1023) rowptr[4096] = ps[1023];
    dinv[b]     = d0 > 0 ? 1.0f / sqrtf((float)d0) : 0.0f;
    dinv[b + 1] = d1 > 0 ? 1.0f / sqrtf((float)d1) : 0.0f;
    dinv[b + 2] = d2 > 0 ? 1.0f / sqrtf((float)d2) : 0.0f;
    dinv[b + 3] = d3 > 0 ? 1.0f / sqrtf((float)d3) : 0.0f;
}

__global__ void edges2_k(const int* __restrict__ ei, const int* __restrict__ rowptr,
                         int* __restrict__ fill, int* __restrict__ colidx, int E) {
    int e = blockIdx.x * 256 + threadIdx.x;
    if (e < E) {
        int r = ei[e], c = ei[E + e];
        int pos = rowptr[r] + atomicAdd(&fill[r], 1);
        colidx[pos] = c;
    }
}

// Sparse per-row top-24 (distinct columns, sorted desc by (val, -col)), diag, y=x.
// One 64-thread block per row; touches only CSR entries (no dense zero/scan).
__global__ void __launch_bounds__(64) rowmax0_k(
        const int* __restrict__ rowptr, const int* __restrict__ colidx,
        const float* __restrict__ dinv, const float* __restrict__ x,
        float* __restrict__ y, float* __restrict__ diag, u64* __restrict__ top24T) {
    const int i = blockIdx.x, t = threadIdx.x;
    __shared__ float row[N];        // touched-sparse
    __shared__ u64 cand[CANDMAX];
    __shared__ int scnt;
    int rs = rowptr[i], re = rowptr[i + 1];
    if (t == 0) { scnt = 0; row[i] = 0.0f; }
    __syncthreads();
    for (int e = rs + t; e < re; e += 64) { int c2 = colidx[e]; if (c2 >= i) row[c2] = 0.0f; }
    __syncthreads();
    for (int e = rs + t; e < re; e += 64) { int c2 = colidx[e]; if (c2 >= i) atomicAdd(&row[c2], 1.0f); }
    __syncthreads();
    float di = dinv[i];
    for (int e = rs + t; e < re; e += 64) {
        int c2 = colidx[e];
        if (c2 > i) {
            float v = -((di * row[c2]) * dinv[c2]);
            int idx = atomicAdd(&scnt, 1);
            if (idx < CANDMAX) cand[idx] = packkey(fabsf(v), (unsigned)c2);
        }
    }
    __syncthreads();
    int L = scnt < CANDMAX ? scnt : CANDMAX;
    for (int r = 0; r < 24; ++r) {
        u64 best = 0ull;
        for (int idx = t; idx < L; idx += 64) { u64 cc = cand[idx]; if (cc > best) best = cc; }
        for (int off = 32; off; off >>= 1) { u64 o = __shfl_xor(best, off, 64); if (o > best) best = o; }
        if (t == 0) top24T[(size_t)r * N + i] = best;
        for (int idx = t; idx < L; idx += 64) { if (cand[idx] == best) cand[idx] = 0ull; }
        __syncthreads();
    }
    if (t == 0) diag[i] = 1.0f - ((di * row[i]) * di);
    y[i * CIN + t] = x[i * CIN + t];
}

// ---------- persistent single-block Jacobi ----------
__global__ void __launch_bounds__(1024) jacobi_k(
        const int* __restrict__ rowptr, const int* __restrict__ colidx,
        const float* __restrict__ dinv,
        float* __restrict__ diag, const u64* __restrict__ top24T, float* __restrict__ y,
        float* __restrict__ rowS, float* __restrict__ colS,
        int* __restrict__ dslotG, int* __restrict__ slistG, int* __restrict__ nslotsG,
        int* __restrict__ rotk, int* __restrict__ rotl,
        float* __restrict__ rotc, float* __restrict__ rotsv) {
    __shared__ float cntK[N], cntL[N];     // 32 KB: counts in, new col values out
    __shared__ u64 rmaxL[N];               // 32 KB, packkey format
    __shared__ float rvalL[N];             // 16 KB (signed value at row argmax)
    __shared__ float diagL[N];             // 16 KB
    __shared__ short dslotL[N];            // 8 KB
    __shared__ u64 rmaxSlot[MAXS];         // slot-row keys, gkey format
    __shared__ u64 w16[16], w16b[16];
    __shared__ float ovRowK[MAXS], ovRowL[MAXS], ovColK[MAXS], ovColL[MAXS];
    __shared__ int slistL[MAXS];
    __shared__ unsigned short sdirty[64];
    __shared__ int S_k, S_l, S_slotk, S_slotl, S_oldk, S_oldl, S_nold, S_ns, S_snd;
    __shared__ float S_c, S_s, S_a2kk, S_a2ll;
    __shared__ u64 S_pivot;
    const int t = threadIdx.x;

    // prologue: init LDS state + first pivot reduce
    u64 mb0 = 0ull;
    for (int i = t; i < N; i += 1024) {
        u64 kk = top24T[i];                // c=0 plane = per-row initial max
        rmaxL[i] = kk;
        rvalL[i] = -__uint_as_float((unsigned)(kk >> 32));
        diagL[i] = diag[i];
        dslotL[i] = -1;
        unsigned col = (~(unsigned)kk) & 4095u;
        u64 gk = gkey((unsigned)(kk >> 32), (unsigned)i, col);
        if (gk > mb0) mb0 = gk;
    }
    if (t == 0) S_ns = 0;
    for (int off = 32; off; off >>= 1) { u64 o = __shfl_down(mb0, off, 64); if (o > mb0) mb0 = o; }
    if ((t & 63) == 0) w16[t >> 6] = mb0;
    __syncthreads();
    if (t == 0) { u64 b = w16[0]; for (int w = 1; w < 16; ++w) if (w16[w] > b) b = w16[w]; S_pivot = b; }
    __syncthreads();

    for (int it = 0; it < ITERS; ++it) {
        // ---- B1: decode pivot, rotation params, 2x2, slot bookkeeping ----
        if (t == 0) {
            unsigned flat = (~(unsigned)S_pivot) & 0xFFFFFFu;
            int k = (int)(flat >> 12), l = (int)(flat & 4095u);
            float akl = rvalL[k];
            float akk = diagL[k], all_ = diagL[l];
            float aDiff = all_ - akk;
            float akl_safe = (akl == 0.0f) ? 1.0f : akl;
            float aDiff_safe = (aDiff == 0.0f) ? 1.0f : aDiff;
            float phi = aDiff / (2.0f * akl_safe);
            float t2 = 1.0f / (fabsf(phi) + sqrtf(phi * phi + 1.0f));
            t2 = (phi < 0.0f) ? -t2 : t2;
            float t1 = akl / aDiff_safe;
            float tt = (fabsf(akl) < fabsf(aDiff) * 1e-36f) ? t1 : t2;
            float cv = 1.0f / sqrtf(tt * tt + 1.0f);
            float sv = tt * cv;
            rotk[it] = k; rotl[it] = l; rotc[it] = cv; rotsv[it] = sv;
            float a1kk = cv * akk - sv * akl;
            float a1kl = sv * akk + cv * akl;
            float a1lk = cv * akl - sv * all_;
            float a1ll = sv * akl + cv * all_;
            S_a2kk = cv * a1kk - sv * a1lk;
            S_a2ll = sv * a1kl + cv * a1ll;
            diagL[k] = S_a2kk; diagL[l] = S_a2ll;
            int ns = S_ns;
            S_nold = ns;
            int ok = dslotL[k]; S_oldk = ok;
            int sk2 = ok; if (ok < 0) { sk2 = ns; slistL[ns] = k; dslotL[k] = (short)ns; ns++; }
            int ol = dslotL[l]; S_oldl = ol;
            int sl3 = ol; if (ol < 0) { sl3 = ns; slistL[ns] = l; dslotL[l] = (short)ns; ns++; }
            S_ns = ns;
            S_k = k; S_l = l; S_slotk = sk2; S_slotl = sl3; S_c = cv; S_s = sv;
            S_snd = 0;
        }
        __syncthreads();
        const int k = S_k, l = S_l, slotk = S_slotk, slotl = S_slotl;
        const int oldk = S_oldk, oldl = S_oldl, nold = S_nold, ns = S_ns;
        const float c = S_c, s = S_s;
        const float a2kk = S_a2kk, a2ll = S_a2ll;
        const bool freshK = (oldk < 0), freshL = (oldl < 0);
        const float dk = dinv[k], dl = dinv[l];
        // ---- B2: y rot, overlay preloads, zero counts ----
        if (t < CIN) {
            float yk = y[k * CIN + t], yl = y[l * CIN + t];
            y[k * CIN + t] = c * yk - s * yl;
            y[l * CIN + t] = s * yk + c * yl;
        }
        if (t >= 64 && t < 64 + nold) {
            int sl2 = t - 64;
            if (freshK) { ovRowK[sl2] = colS[(size_t)sl2 * N + k]; ovColK[sl2] = rowS[(size_t)sl2 * N + k]; }
            if (freshL) { ovRowL[sl2] = colS[(size_t)sl2 * N + l]; ovColL[sl2] = rowS[(size_t)sl2 * N + l]; }
        }
        if (freshK) for (int j = t; j < N; j += 1024) cntK[j] = 0.0f;
        if (freshL) for (int j = t; j < N; j += 1024) cntL[j] = 0.0f;
        __syncthreads();
        // ---- B3: scatter counts for fresh pivots ----
        if (freshK || freshL) {
            if (freshK) for (int e = rowptr[k] + t; e < rowptr[k + 1]; e += 1024) atomicAdd(&cntK[colidx[e]], 1.0f);
            if (freshL) for (int e = rowptr[l] + t; e < rowptr[l + 1]; e += 1024) atomicAdd(&cntL[colidx[e]], 1.0f);
            __syncthreads();
        }
        // ---- (a): build + overlay + rotate + store; stash nck/ncl; bk/bl ----
        u64 bk = packkey(0.0f, 4095u), bl = packkey(0.0f, 4095u);
        {
            const int j0 = t * 4;
            float4 dj4 = *reinterpret_cast<const float4*>(dinv + j0);
            float4 bK4, bL4, cK4, cL4;
            if (freshK) {
                float4 cnt = *reinterpret_cast<const float4*>(cntK + j0);
#pragma unroll
                for (int m = 0; m < 4; ++m) {
                    float cn = (&cnt.x)[m], dj = (&dj4.x)[m];
                    (&bK4.x)[m] = -((dk * cn) * dj);
                    (&cK4.x)[m] = -((dj * cn) * dk);
                }
            } else {
                bK4 = *reinterpret_cast<const float4*>(rowS + (size_t)oldk * N + j0);
                cK4 = *reinterpret_cast<const float4*>(colS + (size_t)oldk * N + j0);
            }
            if (freshL) {
                float4 cnt = *reinterpret_cast<const float4*>(cntL + j0);
#pragma unroll
                for (int m = 0; m < 4; ++m) {
                    float cn = (&cnt.x)[m], dj = (&dj4.x)[m];
                    (&bL4.x)[m] = -((dl * cn) * dj);
                    (&cL4.x)[m] = -((dj * cn) * dl);
                }
            } else {
                bL4 = *reinterpret_cast<const float4*>(rowS + (size_t)oldl * N + j0);
                cL4 = *reinterpret_cast<const float4*>(colS + (size_t)oldl * N + j0);
            }
            float4 nrK4, nrL4, ncK4, ncL4;
#pragma unroll
            for (int m = 0; m < 4; ++m) {
                int j = j0 + m;
                float bK = (&bK4.x)[m], bL = (&bL4.x)[m];
                float cK = (&cK4.x)[m], cL = (&cL4.x)[m];
                float nrk, nrl, nck, ncl;
                if (j == k)      { nrk = a2kk; nrl = 0.0f; nck = a2kk; ncl = 0.0f; }
                else if (j == l) { nrk = 0.0f; nrl = a2ll; nck = 0.0f; ncl = a2ll; }
                else {
                    int sl2 = dslotL[j];
                    if (sl2 >= 0 && sl2 < nold) {
                        if (freshK) { bK = ovRowK[sl2]; cK = ovColK[sl2]; }
                        if (freshL) { bL = ovRowL[sl2]; cL = ovColL[sl2]; }
                    }
                    nrk = c * bK - s * bL; nrl = s * bK + c * bL;
                    nck = c * cK - s * cL; ncl = s * cK + c * cL;
                }
                (&nrK4.x)[m] = nrk; (&nrL4.x)[m] = nrl;
                (&ncK4.x)[m] = nck; (&ncL4.x)[m] = ncl;
                if (j > k) { u64 kk = packkey(fabsf(nrk), (unsigned)j); if (kk > bk) bk = kk; }
                if (j > l) { u64 kk = packkey(fabsf(nrl), (unsigned)j); if (kk > bl) bl = kk; }
            }
            *reinterpret_cast<float4*>(rowS + (size_t)slotk * N + j0) = nrK4;
            *reinterpret_cast<float4*>(rowS + (size_t)slotl * N + j0) = nrL4;
            *reinterpret_cast<float4*>(colS + (size_t)slotk * N + j0) = ncK4;
            *reinterpret_cast<float4*>(colS + (size_t)slotl * N + j0) = ncL4;
            *reinterpret_cast<float4*>(cntK + j0) = ncK4;   // stash for merge
            *reinterpret_cast<float4*>(cntL + j0) = ncL4;
        }
        for (int off = 32; off; off >>= 1) {
            u64 o = __shfl_down(bk, off, 64); if (o > bk) bk = o;
            u64 o2 = __shfl_down(bl, off, 64); if (o2 > bl) bl = o2;
        }
        if ((t & 63) == 0) { w16[t >> 6] = bk; w16b[t >> 6] = bl; }
        __syncthreads();
        // ---- (b)-phase: t0 finalize k/l; patch threads; coalesced merge ----
        if (t == 0) {
            u64 b1 = w16[0], b2 = w16b[0];
            for (int w = 1; w < 16; ++w) { if (w16[w] > b1) b1 = w16[w]; if (w16b[w] > b2) b2 = w16b[w]; }
            unsigned j1 = (~(unsigned)b1) & 4095u, j2 = (~(unsigned)b2) & 4095u;
            rvalL[k] = rowS[(size_t)slotk * N + j1];
            rvalL[l] = rowS[(size_t)slotl * N + j2];
            rmaxSlot[slotk] = gkey((unsigned)(b1 >> 32), (unsigned)k, j1);
            rmaxSlot[slotl] = gkey((unsigned)(b2 >> 32), (unsigned)l, j2);
        }
        if (t >= 64 && t < 64 + nold) {
            int sl2 = t - 64;
            int js = slistL[sl2];
            if (js != k && js != l) {
                float vkj = rowS[(size_t)slotk * N + js];   // new a_{k,js}
                float vlj = rowS[(size_t)slotl * N + js];   // new a_{l,js}
                float vjk = cntK[js];                        // new a_{js,k}
                float vjl = cntL[js];                        // new a_{js,l}
                colS[(size_t)sl2 * N + k] = vkj;
                colS[(size_t)sl2 * N + l] = vlj;
                rowS[(size_t)sl2 * N + k] = vjk;
                rowS[(size_t)sl2 * N + l] = vjl;
                u64 cached = rmaxSlot[sl2];
                unsigned cj = ((~(unsigned)cached) & 0xFFFFFFu) & 4095u;
                bool kc = (k > js), lc = (l > js);
                u64 ck2 = kc ? gkey(__float_as_uint(fabsf(vjk)), (unsigned)js, (unsigned)k) : 0ull;
                u64 cl2 = lc ? gkey(__float_as_uint(fabsf(vjl)), (unsigned)js, (unsigned)l) : 0ull;
                bool stale = false; u64 base = cached; bool useOld = true;
                if (kc && cj == (unsigned)k)      { if (ck2 < cached) stale = true; else { base = 0ull; useOld = false; } }
                else if (lc && cj == (unsigned)l) { if (cl2 < cached) stale = true; else { base = 0ull; useOld = false; } }
                if (!stale) {
                    if (kc || lc) {
                        u64 mm = base; float mv = useOld ? rvalL[js] : 0.0f;
                        if (ck2 > mm) { mm = ck2; mv = vjk; }
                        if (cl2 > mm) { mm = cl2; mv = vjl; }
                        rmaxSlot[sl2] = mm; rvalL[js] = mv;
                    }
                } else { int d2 = atomicAdd(&S_snd, 1); sdirty[d2] = (unsigned short)sl2; }
            }
        }
        u64 myBest = 0ull;
#pragma unroll
        for (int m = 0; m < 4; ++m) {
            int j = t + 1024 * m;
            if (j == k || j == l) continue;
            if (dslotL[j] >= 0) continue;            // slot rows via rmaxSlot
            float nck = cntK[j], ncl = cntL[j];
            u64 cached = rmaxL[j];
            unsigned cj = (~(unsigned)cached) & 4095u;
            bool kc = (k > j), lc = (l > j);
            u64 ck2 = kc ? packkey(fabsf(nck), (unsigned)k) : 0ull;
            u64 cl2 = lc ? packkey(fabsf(ncl), (unsigned)l) : 0ull;
            bool stale = false; u64 base = cached; bool useOld = true;
            if (kc && cj == (unsigned)k)      { if (ck2 < cached) stale = true; else { base = 0ull; useOld = false; } }
            else if (lc && cj == (unsigned)l) { if (cl2 < cached) stale = true; else { base = 0ull; useOld = false; } }
            if (!stale) {
                if (kc || lc) {
                    u64 mm = base; float mv = useOld ? rvalL[j] : 0.0f;
                    if (ck2 > mm) { mm = ck2; mv = nck; }
                    if (cl2 > mm) { mm = cl2; mv = ncl; }
                    rmaxL[j] = mm; rvalL[j] = mv;
                }
            } else {
                // fresh compute: static top-24 probe (early exit) + slots + k/l
                u64 bKey = 0ull; float bVal = 0.0f;
                for (int cc = 0; cc < 24; ++cc) {
                    u64 cand = top24T[(size_t)cc * N + j];
                    unsigned col = (~(unsigned)cand) & 4095u;
                    if (dslotL[col] < 0) {
                        bKey = cand;
                        bVal = -__uint_as_float((unsigned)(cand >> 32));
                        break;
                    }
                }
                for (int sl = 0; sl < ns; ++sl) {
                    if (sl == slotk || sl == slotl) continue;
                    int js = slistL[sl];
                    if (js > j) {
                        float v = colS[(size_t)sl * N + j];
                        u64 kk2 = packkey(fabsf(v), (unsigned)js);
                        if (kk2 > bKey) { bKey = kk2; bVal = v; }
                    }
                }
                if (kc && ck2 > bKey) { bKey = ck2; bVal = nck; }
                if (lc && cl2 > bKey) { bKey = cl2; bVal = ncl; }
                rmaxL[j] = bKey; rvalL[j] = bVal;
            }
            u64 fin = rmaxL[j];
            u64 gk = gkey((unsigned)(fin >> 32), (unsigned)j, (~(unsigned)fin) & 4095u);
            if (gk > myBest) myBest = gk;
        }
        __syncthreads();
        // ---- B6: dirty slot-row rescans (rare) ----
        const int nd = S_snd;
        for (int d = 0; d < nd; ++d) {
            int sl2 = sdirty[d];
            int ir = slistL[sl2];
            u64 bb = packkey(0.0f, 4095u);
            int jb = t * 4;
            float4 v4 = *reinterpret_cast<const float4*>(rowS + (size_t)sl2 * N + jb);
#pragma unroll
            for (int m = 0; m < 4; ++m) {
                int j = jb + m;
                if (j > ir) {
                    u64 kk = packkey(fabsf((&v4.x)[m]), (unsigned)j);
                    if (kk > bb) bb = kk;
                }
            }
            for (int off = 32; off; off >>= 1) { u64 o = __shfl_down(bb, off, 64); if (o > bb) bb = o; }
            if ((t & 63) == 0) w16[t >> 6] = bb;
            __syncthreads();
            if (t == 0) {
                u64 b = w16[0];
                for (int w = 1; w < 16; ++w) if (w16[w] > b) b = w16[w];
                unsigned js2 = (~(unsigned)b) & 4095u;
                rmaxSlot[sl2] = gkey((unsigned)(b >> 32), (unsigned)ir, js2);
                rvalL[ir] = rowS[(size_t)sl2 * N + js2];
            }
            __syncthreads();
        }
        // ---- B7: final pivot reduce (normal rows + slot rows incl. k,l) ----
        if (t < ns) { u64 o = rmaxSlot[t]; if (o > myBest) myBest = o; }
        for (int off = 32; off; off >>= 1) { u64 o = __shfl_down(myBest, off, 64); if (o > myBest) myBest = o; }
        if ((t & 63) == 0) w16[t >> 6] = myBest;
        __syncthreads();
        if (t == 0) { u64 b = w16[0]; for (int w = 1; w < 16; ++w) if (w16[w] > b) b = w16[w]; S_pivot = b; }
        __syncthreads();
    }
    // epilogue: mirror state for tail kernels
    for (int i = t; i < N; i += 1024) {
        diag[i] = diagL[i];
        dslotG[i] = (int)dslotL[i];
    }
    if (t < S_ns) slistG[t] = slistL[t];
    if (t == 0) *nslotsG = S_ns;
}

// ---------- tail ----------
__global__ void __launch_bounds__(1024) spectral_k(
        const float* __restrict__ diag, const float* __restrict__ y,
        const float2* __restrict__ hcT, const float4* __restrict__ rwT,
        const float4* __restrict__ iwT, float* __restrict__ z) {
    int o = threadIdx.x & 63;
    int nl = threadIdx.x >> 6;
    int n = blockIdx.x * 16 + nl;
    __shared__ float saux[16][CIN];
    saux[nl][o] = y[n * CIN + o];
    __syncthreads();
    float wn = diag[n];
    const float C2 = -0.41614683654714241f;   // cos(2.0)
    const float S2 = 0.90929742682568170f;    // sin(2.0)
    float acc = 0.0f;
    for (int i = 0; i < CIN; ++i) {
        float2 hc = hcT[i * 64 + o];
        float hw = hc.x * wn;
        float t2v = hw * hw;
        float inv = 1.0f / (t2v + 1.0f);
        float c1 = (t2v - 1.0f) * inv;
        float s1 = (2.0f * hw) * inv;
        if (!(hw > 1e-5f)) { c1 = C2; s1 = S2; }
        float4 rwv = rwT[i * 64 + o];
        float4 iwv = iwT[i * 64 + o];
        float g = hc.y;
        float cj = c1, sj = s1;
        g += rwv.x * cj - iwv.x * sj;
        float cn = cj * c1 - sj * s1; float sn = sj * c1 + cj * s1; cj = cn; sj = sn;
        g += rwv.y * cj - iwv.y * sj;
        cn = cj * c1 - sj * s1; sn = sj * c1 + cj * s1; cj = cn; sj = sn;
        g += rwv.z * cj - iwv.z * sj;
        cn = cj * c1 - sj * s1; sn = sj * c1 + cj * s1; cj = cn; sj = sn;
        g += rwv.w * cj - iwv.w * sj;
        acc += g * saux[nl][i];
    }
    z[(size_t)n * COUT + o] = acc;
}

// Fused finalrot + bias + store.
__global__ void store_fused_k(
        float* __restrict__ z, const float* __restrict__ bias,
        const int* __restrict__ dslot, const int* __restrict__ slistG,
        const int* __restrict__ nslotsG,
        const int* __restrict__ rotk, const int* __restrict__ rotl,
        const float* __restrict__ rotc, const float* __restrict__ rotsv,
        float* __restrict__ out) {
    int t = threadIdx.x;
    if (blockIdx.x < 1024) {
        int idx = blockIdx.x * 256 + t;
        int row = idx >> 6;
        if (dslot[row] < 0) out[idx] = z[idx] + bias[idx & 63];
    } else if (t < 64) {
        for (int i = ITERS - 1; i >= 0; --i) {
            int k = rotk[i], l = rotl[i];
            float c = rotc[i], s = rotsv[i];
            float zk = z[k * COUT + t];
            float zl = z[l * COUT + t];
            z[k * COUT + t] = c * zk + s * zl;
            z[l * COUT + t] = -s * zk + c * zl;
        }
        int ns = *nslotsG;
        for (int d = 0; d < ns; ++d) {
            int r = slistG[d];
            out[r * COUT + t] = z[r * COUT + t] + bias[t];
        }
    }
}

extern "C" void kernel_launch(void* const* d_in, const int* in_sizes, int n_in,
                              void* d_out, int out_size, void* d_ws, size_t ws_size,
                              hipStream_t stream) {
    const float* x   = (const float*)d_in[0];
    const int*   ei  = (const int*)d_in[1];
    const float* rw  = (const float*)d_in[2];
    const float* iw  = (const float*)d_in[3];
    const float* hh  = (const float*)d_in[4];
    const float* cw  = (const float*)d_in[5];
    const float* bias= (const float*)d_in[6];
    float* out = (float*)d_out;

    // Workspace carve (~6.1 MB)
    float* rowS = (float*)d_ws;                 // MAXS*N
    float* colS = rowS + (size_t)MAXS * N;      // MAXS*N
    float* y    = colS + (size_t)MAXS * N;      // N*CIN
    float* z    = y + N * CIN;                  // N*COUT
    float2* hcT = (float2*)(z + N * COUT);      // 4096 float2
    float4* rwT = (float4*)(hcT + 4096);        // 4096 float4
    float4* iwT = rwT + 4096;                   // 4096 float4
    float* dinv = (float*)(iwT + 4096);         // 4096
    float* diag = dinv + N;                     // 4096
    u64* top24T = (u64*)(diag + N);             // 24*N u64
    int* rowptr = (int*)(top24T + 24 * (size_t)N); // 4097 (+pad)
    int* fill   = rowptr + 4100;                // 4096
    int* deg    = fill + N;                     // 4096
    int* slist  = deg + N;                      // 64
    int* nslots = slist + 64;                   // 4
    int* dslot  = nslots + 4;                   // 4096
    int* rotk   = dslot + N;                    // 16
    int* rotl   = rotk + 16;                    // 16
    float* rotc = (float*)(rotl + 16);          // 16
    float* rotsv= rotc + 16;                    // 16
    int* colidx = (int*)(rotsv + 16);           // E

    int E = in_sizes[1] / 2;                    // row half of edge_index
    int eb = (E + 255) / 256;

    init_prep_k<<<32, 256, 0, stream>>>(deg, fill, hh, cw, rw, iw, hcT, rwT, iwT);
    edges1_k<<<eb, 256, 0, stream>>>(ei, deg, E);
    scan_k<<<1, 1024, 0, stream>>>(deg, rowptr, dinv);
    edges2_k<<<eb, 256, 0, stream>>>(ei, rowptr, fill, colidx, E);
    rowmax0_k<<<N, 64, 0, stream>>>(rowptr, colidx, dinv, x, y, diag, top24T);

    jacobi_k<<<1, 1024, 0, stream>>>(rowptr, colidx, dinv, diag, top24T,
                                     y, rowS, colS, dslot, slist, nslots,
                                     rotk, rotl, rotc, rotsv);

    spectral_k<<<N / 16, 1024, 0, stream>>>(diag, y, hcT, rwT, iwT, z);
    store_fused_k<<<1025, 256, 0, stream>>>(z, bias, dslot, slist, nslots,
                                            rotk, rotl, rotc, rotsv, out);
}